// Round 4
// baseline (471.527 us; speedup 1.0000x reference)
//
#include <hip/hip_runtime.h>

#define NN 52500
#define NP 36500            // nodes with children (levels 0..4) = parents
#define E0 500              // edge e corresponds to src node n = e + 500

__device__ __forceinline__ float sigmoidf_(float x) { return 1.f / (1.f + __expf(-x)); }
__device__ __forceinline__ float tanhf_(float x) {
    float e = __expf(-2.f * fabsf(x));
    return copysignf((1.f - e) / (1.f + e), x);
}

typedef __attribute__((ext_vector_type(8))) short bf16x8;
typedef __attribute__((ext_vector_type(4))) float f32x4;

__device__ __forceinline__ unsigned short f2bf_rne(float f) {
    unsigned int u = __float_as_uint(f);
    u += 0x7FFF + ((u >> 16) & 1);
    return (unsigned short)(u >> 16);
}

// load 8 consecutive f32, split each into bf16 hi + bf16 lo (compensated precision ~2^-17)
__device__ __forceinline__ void load_split(const float* p, bf16x8& hi, bf16x8& lo) {
    float4 a = *(const float4*)p;
    float4 b = *(const float4*)(p + 4);
    float v[8] = {a.x, a.y, a.z, a.w, b.x, b.y, b.z, b.w};
#pragma unroll
    for (int j = 0; j < 8; ++j) {
        unsigned short hu = f2bf_rne(v[j]);
        float hf = __uint_as_float((unsigned int)hu << 16);
        hi[j] = (short)hu;
        lo[j] = (short)f2bf_rne(v[j] - hf);
    }
}

__global__ __launch_bounds__(256) void zero_kernel(float* __restrict__ p, int n4) {
    int i = blockIdx.x * 256 + threadIdx.x;
    if (i < n4) ((float4*)p)[i] = (float4){0.f, 0.f, 0.f, 0.f};
}

// x_f = x @ W_f^T + b_f for nodes 0..NP-1, f32 out, compensated bf16 MFMA
__global__ __launch_bounds__(256) void xfproj_kernel(
    const float* __restrict__ x, const float* __restrict__ Wf,
    const float* __restrict__ bfp, float* __restrict__ xf)
{
    int wave = threadIdx.x >> 6, lane = threadIdx.x & 63;
    int l15 = lane & 15, quad = lane >> 4;
    int rowBase = blockIdx.x * 64 + wave * 16;

    int arow = rowBase + l15;
    if (arow >= NP) arow = NP - 1;
    const float* ap = x + (size_t)arow * 128 + quad * 8;
    bf16x8 ahi[4], alo[4];
#pragma unroll
    for (int kt = 0; kt < 4; ++kt) load_split(ap + kt * 32, ahi[kt], alo[kt]);

    f32x4 acc[4];
#pragma unroll
    for (int ct = 0; ct < 4; ++ct) acc[ct] = (f32x4){0.f, 0.f, 0.f, 0.f};

#pragma unroll
    for (int ct = 0; ct < 4; ++ct) {
        int col = ct * 16 + l15;
        const float* bp = Wf + (size_t)col * 128 + quad * 8;
#pragma unroll
        for (int kt = 0; kt < 4; ++kt) {
            bf16x8 bhi, blo;
            load_split(bp + kt * 32, bhi, blo);
            acc[ct] = __builtin_amdgcn_mfma_f32_16x16x32_bf16(ahi[kt], bhi, acc[ct], 0, 0, 0);
            acc[ct] = __builtin_amdgcn_mfma_f32_16x16x32_bf16(ahi[kt], blo, acc[ct], 0, 0, 0);
            acc[ct] = __builtin_amdgcn_mfma_f32_16x16x32_bf16(alo[kt], bhi, acc[ct], 0, 0, 0);
        }
    }

    // C/D: col = lane&15 (+16*ct), row = quad*4 + reg
#pragma unroll
    for (int ct = 0; ct < 4; ++ct) {
        int col = ct * 16 + l15;
        float bias = bfp[col];
#pragma unroll
        for (int r = 0; r < 4; ++r) {
            int n = rowBase + quad * 4 + r;
            if (n < NP) xf[(size_t)n * 64 + col] = acc[ct][r] + bias;
        }
    }
}

// per level: x_iou (192 cols, in-register) + Uh_sum/fc_sum -> cell -> h,c (f32 to d_out)
__global__ __launch_bounds__(256) void projcell_kernel(
    const float* __restrict__ x, const float* __restrict__ Wiou,
    const float* __restrict__ biou,
    const float* __restrict__ uh, const float* __restrict__ fcs,
    float* __restrict__ h_all, float* __restrict__ c_all,
    int s0, int s1, int read_sums)
{
    int wave = threadIdx.x >> 6, lane = threadIdx.x & 63;
    int l15 = lane & 15, quad = lane >> 4;
    int rowBase = blockIdx.x * 64 + wave * 16;    // relative to s0

    int arow = s0 + rowBase + l15;
    if (arow >= s1) arow = s1 - 1;
    const float* ap = x + (size_t)arow * 128 + quad * 8;
    bf16x8 ahi[4], alo[4];
#pragma unroll
    for (int kt = 0; kt < 4; ++kt) load_split(ap + kt * 32, ahi[kt], alo[kt]);

    f32x4 acc[12];
#pragma unroll
    for (int ct = 0; ct < 12; ++ct) acc[ct] = (f32x4){0.f, 0.f, 0.f, 0.f};

#pragma unroll
    for (int ct = 0; ct < 12; ++ct) {
        int col = ct * 16 + l15;
        const float* bp = Wiou + (size_t)col * 128 + quad * 8;
#pragma unroll
        for (int kt = 0; kt < 4; ++kt) {
            bf16x8 bhi, blo;
            load_split(bp + kt * 32, bhi, blo);
            acc[ct] = __builtin_amdgcn_mfma_f32_16x16x32_bf16(ahi[kt], bhi, acc[ct], 0, 0, 0);
            acc[ct] = __builtin_amdgcn_mfma_f32_16x16x32_bf16(ahi[kt], blo, acc[ct], 0, 0, 0);
            acc[ct] = __builtin_amdgcn_mfma_f32_16x16x32_bf16(alo[kt], bhi, acc[ct], 0, 0, 0);
        }
    }

    // lane (l15,quad) holds, for node row quad*4+r, h-cols j = 16g + l15 (g=0..3):
    //   i = acc[g], o = acc[4+g], u = acc[8+g]
#pragma unroll
    for (int g = 0; g < 4; ++g) {
        int j = g * 16 + l15;
        float bi = biou[j], bo = biou[64 + j], bu = biou[128 + j];
#pragma unroll
        for (int r = 0; r < 4; ++r) {
            int n = s0 + rowBase + quad * 4 + r;
            if (n < s1) {
                float iv = acc[g][r] + bi;
                float ov = acc[4 + g][r] + bo;
                float uv = acc[8 + g][r] + bu;
                float ui = 0.f, uo = 0.f, uu = 0.f, fc0 = 0.f;
                if (read_sums) {
                    size_t b = (size_t)n * 192;
                    ui = uh[b + j]; uo = uh[b + 64 + j]; uu = uh[b + 128 + j];
                    fc0 = fcs[(size_t)n * 64 + j];
                }
                float c = sigmoidf_(iv + ui) * tanhf_(uv + uu) + fc0;
                float h = sigmoidf_(ov + uo) * tanhf_(c);
                h_all[(size_t)n * 64 + j] = h;
                c_all[(size_t)n * 64 + j] = c;
            }
        }
    }
}

// one wave per node: hf = h·U_f[mid], Uh = h·U_iou[mid]; scatter-add to parent (f32 atomics)
__global__ __launch_bounds__(256) void edge_kernel(
    const float* __restrict__ h_all, const float* __restrict__ c_all,
    const float* __restrict__ xf,
    float* __restrict__ uh, float* __restrict__ fcs,
    const float* __restrict__ Uiou, const float* __restrict__ Ufm,
    const int* __restrict__ edge_dst, const int* __restrict__ mat_id,
    int s0, int s1)
{
    __shared__ float hbuf[4][64];
    __shared__ float cbuf[4][64];
    int wid = threadIdx.x >> 6, lane = threadIdx.x & 63;
    int n = s0 + blockIdx.x * 4 + wid;
    if (n >= s1) return;

    hbuf[wid][lane] = h_all[(size_t)n * 64 + lane];  // wave-private LDS, in-order DS ops
    cbuf[wid][lane] = c_all[(size_t)n * 64 + lane];

    int e = n - E0;                 // src == n by construction
    int dst = edge_dst[e];
    int mid = mat_id[e];

    // lanes 0..47: U_iou cols 4L..4L+3 (192); lanes 48..63: U_f cols 4(L-48)..+3 (64)
    bool isf = (lane >= 48);
    int cb = isf ? 4 * (lane - 48) : 4 * lane;
    const float* p = isf ? (Ufm + (size_t)mid * 4096 + cb)
                         : (Uiou + (size_t)mid * 12288 + cb);
    int stride = isf ? 64 : 192;

    float a0 = 0.f, a1 = 0.f, a2 = 0.f, a3 = 0.f;
    for (int k = 0; k < 64; k += 4) {
        float4 hv = *(const float4*)&hbuf[wid][k];
#pragma unroll
        for (int t = 0; t < 4; ++t) {
            float4 u = *(const float4*)p;   // 16 B/lane, coalesced
            p += stride;
            float hvt = ((const float*)&hv)[t];
            a0 += hvt * u.x; a1 += hvt * u.y; a2 += hvt * u.z; a3 += hvt * u.w;
        }
    }

    if (isf) {
        size_t d = (size_t)dst * 64 + cb;   // xf and fcs share indexing
        float4 cv = *(const float4*)&cbuf[wid][cb];
        atomicAdd(&fcs[d + 0], sigmoidf_(xf[d + 0] + a0) * cv.x);
        atomicAdd(&fcs[d + 1], sigmoidf_(xf[d + 1] + a1) * cv.y);
        atomicAdd(&fcs[d + 2], sigmoidf_(xf[d + 2] + a2) * cv.z);
        atomicAdd(&fcs[d + 3], sigmoidf_(xf[d + 3] + a3) * cv.w);
    } else {
        size_t d = (size_t)dst * 192 + cb;
        atomicAdd(&uh[d + 0], a0);
        atomicAdd(&uh[d + 1], a1);
        atomicAdd(&uh[d + 2], a2);
        atomicAdd(&uh[d + 3], a3);
    }
}

extern "C" void kernel_launch(void* const* d_in, const int* in_sizes, int n_in,
                              void* d_out, int out_size, void* d_ws, size_t ws_size,
                              hipStream_t stream) {
    const float* x      = (const float*)d_in[0];
    // d_in[1] = edge_src == arange(500, 52500) -> unused
    const int* edge_dst = (const int*)d_in[2];
    const int* mat_id   = (const int*)d_in[3];
    const float* Wiou   = (const float*)d_in[4];
    const float* biou   = (const float*)d_in[5];
    const float* Wf     = (const float*)d_in[6];
    const float* bfp    = (const float*)d_in[7];
    const float* Uiou   = (const float*)d_in[8];
    const float* Ufm    = (const float*)d_in[9];

    // ws (f32): [uh: NP*192][fcs: NP*64][xf: NP*64]  = 46.7 MB total
    float* uh  = (float*)d_ws;
    float* fcs = uh + (size_t)NP * 192;
    float* xf  = fcs + (size_t)NP * 64;

    float* out_h = (float*)d_out;            // f32 output: h then c
    float* out_c = out_h + (size_t)NN * 64;

    // zero uh+fcs (contiguous: NP*256 floats)
    int n4 = (int)((size_t)NP * 256 / 4);
    zero_kernel<<<(n4 + 255) / 256, 256, 0, stream>>>(uh, n4);

    xfproj_kernel<<<(NP + 63) / 64, 256, 0, stream>>>(x, Wf, bfp, xf);

    static const int noff[7] = {0, 500, 2500, 8500, 20500, 36500, 52500};
    for (int l = 5; l >= 0; --l) {
        int s0 = noff[l], s1 = noff[l + 1], nl = s1 - s0;
        projcell_kernel<<<(nl + 63) / 64, 256, 0, stream>>>(
            x, Wiou, biou, uh, fcs, out_h, out_c, s0, s1, (l != 5) ? 1 : 0);
        if (l >= 1) {
            edge_kernel<<<(nl + 3) / 4, 256, 0, stream>>>(
                out_h, out_c, xf, uh, fcs, Uiou, Ufm, edge_dst, mat_id, s0, s1);
        }
    }
}